// Round 15
// baseline (304.568 us; speedup 1.0000x reference)
//
#include <hip/hip_runtime.h>
#include <hip/hip_bf16.h>
#include <cmath>

#define T_DIM 512
#define N_DIM 512
#define M_DIM 256
#define B_DIM 256

typedef __bf16 bf16x8 __attribute__((ext_vector_type(8)));
typedef float  f32x4  __attribute__((ext_vector_type(4)));
typedef unsigned int u32;

#define WAITVM(N) asm volatile("s_waitcnt vmcnt(" #N ") lgkmcnt(0)" ::: "memory")
#define FENCED_BARRIER() do { __builtin_amdgcn_sched_barrier(0); \
                              __builtin_amdgcn_s_barrier();      \
                              __builtin_amdgcn_sched_barrier(0); } while (0)

__device__ __forceinline__ void gload16(const __bf16* g, __bf16* l) {
    __builtin_amdgcn_global_load_lds(
        (const __attribute__((address_space(1))) void*)g,
        (__attribute__((address_space(3))) void*)l, 16, 0, 0);
}

__device__ __forceinline__ int bkey(int r) { return ((r >> 3) ^ (r >> 1)) & 3; }

__device__ __forceinline__ u32 pack_trunc(float hi, float lo) {
    return __builtin_amdgcn_perm(__builtin_bit_cast(u32, hi),
                                 __builtin_bit_cast(u32, lo), 0x07060302u);
}

__device__ __forceinline__ float ftanh(float x) {
    return 1.f - 2.f / (__expf(2.f * x) + 1.f);
}

// ---------------- precompute: U_e -> bf16 ----------------
__global__ __launch_bounds__(256) void uconv_kernel(
    const float* __restrict__ U, __bf16* __restrict__ Uh)
{
    const int i = (blockIdx.x * 256 + threadIdx.x) * 2;
    float2 v = *(const float2*)(U + i);
    Uh[i]   = (__bf16)v.x;
    Uh[i+1] = (__bf16)v.y;
}

// ---------------- wq[b,t] = concat(h,s) . W_e[t,:] ----------------
__global__ __launch_bounds__(256) void wq_kernel(
    const float* __restrict__ h_t, const float* __restrict__ s_t,
    const float* __restrict__ W_e, float* __restrict__ wq)
{
    __shared__ float q[2 * M_DIM];
    const int b = blockIdx.x;
    const int tid = threadIdx.x;
    q[tid]         = h_t[(size_t)b * M_DIM + tid];
    q[M_DIM + tid] = s_t[(size_t)b * M_DIM + tid];
    __syncthreads();
    for (int tt = tid; tt < T_DIM; tt += 256) {
        const float4* wrow = (const float4*)(W_e + (size_t)tt * (2 * M_DIM));
        float acc = 0.f;
        #pragma unroll 4
        for (int k4 = 0; k4 < (2 * M_DIM) / 4; ++k4) {
            float4 w = wrow[k4];
            acc += q[4*k4+0] * w.x + q[4*k4+1] * w.y
                 + q[4*k4+2] * w.z + q[4*k4+3] * w.w;
        }
        wq[(size_t)b * T_DIM + tt] = acc;
    }
}

// ---------------- fused: R14 + pa depth-2 (two named reg sets) ----------------
// pa(T) loaded at step T-3 (age 2 steps); B(T) staged at step T-2 on 3-ring.
// Steady step: CVT(pa(k+1)) [compiler vmcnt(6), retires only pa] ->
// STAGE_B(k+2) -> LOAD_PA(k+3) -> MFMA -> WAITVM(8) [retires only B(k+1)] -> barrier.
__global__ __launch_bounds__(512, 2) void fused13_kernel(
    const float* __restrict__ data, const __bf16* __restrict__ Uh,
    const float* __restrict__ v_e, const float* __restrict__ wq,
    float* __restrict__ scores)
{
    __shared__ __align__(16) __bf16 As[2][128 * 32];   // 16 KB
    __shared__ __align__(16) __bf16 Bs[3][512 * 32];   // 96 KB (3-ring)
    __shared__ float sc2[4][128];

    const int wg   = blockIdx.x;
    const int bgrp = wg >> 2;
    const int nb   = wg & 3;

    const int tid  = threadIdx.x;
    const int lane = tid & 63;
    const int wid  = tid >> 6;
    const int wm   = wid >> 2;           // n-half
    const int wn   = wid & 3;            // s-quarter

    f32x4 acc[4][8];
    const f32x4 zero = {0.f, 0.f, 0.f, 0.f};
    #pragma unroll
    for (int i = 0; i < 4; ++i)
        #pragma unroll
        for (int j = 0; j < 8; ++j)
            acc[i][j] = zero;

    // A staging map (R11): rp = t-pair, nq -> 4 n rows, 32-lane coalesced
    const int rp = tid >> 5;
    const int nq = tid & 31;
    const int n0 = nq * 4;
    const float* Apan = data + ((size_t)bgrp * 4 * T_DIM) * N_DIM + nb * 128 + n0;

    // B staging (R9): source-side chunk swizzle, linear LDS dest
    const __bf16* Bb = Uh;
    const int r0   = tid >> 2;
    const int ce   = (((tid & 3) ^ bkey(r0)) * 8);

    const int fr = lane & 15;
    const int kb = (lane >> 4) * 8;

    int aoff[4];
    #pragma unroll
    for (int mi = 0; mi < 4; ++mi) {
        const int row = wm * 64 + mi * 16 + fr;
        aoff[mi] = row * 32 + (kb ^ (bkey(row) << 3));
    }
    int boff[8];
    #pragma unroll
    for (int ni = 0; ni < 8; ++ni) {
        const int row = wn * 128 + ni * 16 + fr;
        boff[ni] = row * 32 + (kb ^ (bkey(row) << 3));
    }

    const int g = lane >> 4;

    // two pa register sets (set = tile&1): consume-then-reload same set per step
    float4 pa0A, pa1A, pa0B, pa1B;

#define CVT_STORE(DST, P0, P1)                                                \
    {                                                                         \
        u32* As32_ = (u32*)(DST);                                             \
        const float lo_[4] = {(P0).x, (P0).y, (P0).z, (P0).w};                \
        const float hi_[4] = {(P1).x, (P1).y, (P1).z, (P1).w};                \
        _Pragma("unroll")                                                     \
        for (int j = 0; j < 4; ++j) {                                         \
            const u32 w_ = pack_trunc(hi_[j], lo_[j]);                        \
            const int key_ = bkey(n0 + j);                                    \
            As32_[(n0 + j) * 16 + (rp ^ (key_ << 2))] = w_;                   \
        }                                                                     \
    }

#define LOAD_PA(T, P0, P1)                                                    \
    {                                                                         \
        const float* sn_ = Apan + (size_t)(32 * (T) + 2 * rp) * N_DIM;        \
        (P0) = *(const float4*)sn_;                                           \
        (P1) = *(const float4*)(sn_ + N_DIM);                                 \
    }

#define STAGE_B(T, RING)                                                      \
    {                                                                         \
        const int kcol_ = ((T) & 15) << 5;                                    \
        _Pragma("unroll")                                                     \
        for (int i = 0; i < 4; ++i)                                           \
            gload16(Bb + (size_t)(i * 128 + r0) * T_DIM + kcol_ + ce,         \
                    &Bs[RING][0] + (size_t)i * 128 * 32 + tid * 8);           \
    }

// MODE 0: steady  (CVT, STAGE_B(K+2), LOAD_PA(K+3), WAITVM(8))
// MODE 3: k==61   (CVT, STAGE_B(63),               WAITVM(6))
// MODE 1: k==62   (CVT,                            WAITVM(0))
// MODE 2: k==63   (compute only, no barrier)
#define K_STEP(K, CURA, RINGC, RINGS, MODE, P0, P1)                           \
    {                                                                         \
        bf16x8 a_[4], bv_[8];                                                 \
        _Pragma("unroll")                                                     \
        for (int mi = 0; mi < 4; ++mi)                                        \
            a_[mi] = *(const bf16x8*)&As[CURA][aoff[mi]];                     \
        _Pragma("unroll")                                                     \
        for (int ni = 0; ni < 8; ++ni)                                        \
            bv_[ni] = *(const bf16x8*)&Bs[RINGC][boff[ni]];                   \
        if ((MODE) != 2) CVT_STORE(As[(CURA) ^ 1], P0, P1);                   \
        if ((MODE) == 0 || (MODE) == 3) STAGE_B((K) + 2, RINGS);              \
        if ((MODE) == 0) LOAD_PA((K) + 3, P0, P1);                            \
        __builtin_amdgcn_s_setprio(1);                                        \
        _Pragma("unroll")                                                     \
        for (int mi = 0; mi < 4; ++mi)                                        \
            _Pragma("unroll")                                                 \
            for (int ni = 0; ni < 8; ++ni)                                    \
                acc[mi][ni] = __builtin_amdgcn_mfma_f32_16x16x32_bf16(        \
                    a_[mi], bv_[ni], acc[mi][ni], 0, 0, 0);                   \
        __builtin_amdgcn_s_setprio(0);                                        \
        if ((MODE) == 0)      { WAITVM(8); FENCED_BARRIER(); }                \
        else if ((MODE) == 3) { WAITVM(6); FENCED_BARRIER(); }                \
        else if ((MODE) == 1) { WAITVM(0); FENCED_BARRIER(); }                \
    }

#define PANEL_EPI(BIDX, DORESET)                                              \
    {                                                                         \
        const int b_ = bgrp * 4 + (BIDX);                                     \
        float wqv_[8], vev_[8];                                               \
        _Pragma("unroll")                                                     \
        for (int ni = 0; ni < 8; ++ni) {                                      \
            const int scol_ = wn * 128 + ni * 16 + fr;                        \
            wqv_[ni] = wq[(size_t)b_ * T_DIM + scol_];                        \
            vev_[ni] = v_e[scol_];                                            \
        }                                                                     \
        _Pragma("unroll")                                                     \
        for (int mi = 0; mi < 4; ++mi) {                                      \
            _Pragma("unroll")                                                 \
            for (int rg = 0; rg < 4; ++rg) {                                  \
                float part_ = 0.f;                                            \
                _Pragma("unroll")                                             \
                for (int ni = 0; ni < 8; ++ni)                                \
                    part_ += vev_[ni] * ftanh(wqv_[ni] + acc[mi][ni][rg]);    \
                part_ += __shfl_xor(part_, 1);                                \
                part_ += __shfl_xor(part_, 2);                                \
                part_ += __shfl_xor(part_, 4);                                \
                part_ += __shfl_xor(part_, 8);                                \
                if (fr == 0)                                                  \
                    sc2[wn][wm * 64 + mi * 16 + 4 * g + rg] = part_;          \
            }                                                                 \
        }                                                                     \
        asm volatile("s_waitcnt lgkmcnt(0)" ::: "memory");                    \
        FENCED_BARRIER();                                                     \
        if (tid < 128) {                                                      \
            const float s_ = sc2[0][tid] + sc2[1][tid]                        \
                           + sc2[2][tid] + sc2[3][tid];                       \
            scores[(size_t)b_ * N_DIM + nb * 128 + tid] = s_;                 \
        }                                                                     \
        if (DORESET) {                                                        \
            _Pragma("unroll")                                                 \
            for (int i = 0; i < 4; ++i)                                       \
                _Pragma("unroll")                                             \
                for (int j = 0; j < 8; ++j)                                   \
                    acc[i][j] = zero;                                         \
        }                                                                     \
    }

    // ---- prologue: cvt tile0 -> As[0]; B(0),B(1) staged; pa(1)->setB, pa(2)->setA
    {
        float4 pl0, pl1;
        LOAD_PA(0, pl0, pl1);
        CVT_STORE(As[0], pl0, pl1);      // waits only the pl loads
    }
    STAGE_B(0, 0);
    STAGE_B(1, 1);
    LOAD_PA(1, pa0B, pa1B);              // tile 1 -> set1 (B)
    LOAD_PA(2, pa0A, pa1A);              // tile 2 -> set0 (A)
    WAITVM(8);                           // retire B(0); keep B(1), pa(1), pa(2)
    FENCED_BARRIER();

    // ---- main loop: k = 0..59 (unroll 6: static As-parity, ring, pa-set)
    // k even -> set (k+1)&1 = 1 (B regs); k odd -> set 0 (A regs)
    for (int m = 0; m < 10; ++m) {
        const int k6 = 6 * m;
        K_STEP(k6 + 0, 0, 0, 2, 0, pa0B, pa1B); if (((k6 + 0) & 15) == 15) PANEL_EPI((k6 + 0) >> 4, 1);
        K_STEP(k6 + 1, 1, 1, 0, 0, pa0A, pa1A); if (((k6 + 1) & 15) == 15) PANEL_EPI((k6 + 1) >> 4, 1);
        K_STEP(k6 + 2, 0, 2, 1, 0, pa0B, pa1B); if (((k6 + 2) & 15) == 15) PANEL_EPI((k6 + 2) >> 4, 1);
        K_STEP(k6 + 3, 1, 0, 2, 0, pa0A, pa1A); if (((k6 + 3) & 15) == 15) PANEL_EPI((k6 + 3) >> 4, 1);
        K_STEP(k6 + 4, 0, 1, 0, 0, pa0B, pa1B); if (((k6 + 4) & 15) == 15) PANEL_EPI((k6 + 4) >> 4, 1);
        K_STEP(k6 + 5, 1, 2, 1, 0, pa0A, pa1A); if (((k6 + 5) & 15) == 15) PANEL_EPI((k6 + 5) >> 4, 1);
    }

    // ---- peeled tail: k = 60..63
    K_STEP(60, 0, 0, 2, 0, pa0B, pa1B);  // CVT(61), STAGE_B(62), LOAD_PA(63)->setB
    K_STEP(61, 1, 1, 0, 3, pa0A, pa1A);  // CVT(62) [waits pa(62)], STAGE_B(63), vmcnt(6)
    K_STEP(62, 0, 2, 0, 1, pa0B, pa1B);  // CVT(63) [waits pa(63)], vmcnt(0)
    K_STEP(63, 1, 0, 0, 2, pa0A, pa1A);  // compute only
    PANEL_EPI(3, 0);

#undef K_STEP
#undef PANEL_EPI
#undef CVT_STORE
#undef LOAD_PA
#undef STAGE_B
}

// ---------------- softmax over n ----------------
__global__ __launch_bounds__(512) void softmax_kernel(
    const float* __restrict__ scores, float* __restrict__ out)
{
    const int b = blockIdx.x;
    const int n = threadIdx.x;
    float s = scores[(size_t)b * N_DIM + n];

    float m = s;
    #pragma unroll
    for (int off = 1; off < 64; off <<= 1)
        m = fmaxf(m, __shfl_xor(m, off));
    __shared__ float red[8];
    const int wv = n >> 6;
    if ((n & 63) == 0) red[wv] = m;
    __syncthreads();
    float bm = red[0];
    #pragma unroll
    for (int i = 1; i < 8; ++i) bm = fmaxf(bm, red[i]);

    float e = expf(s - bm);
    float t = e;
    #pragma unroll
    for (int off = 1; off < 64; off <<= 1)
        t += __shfl_xor(t, off);
    __syncthreads();
    if ((n & 63) == 0) red[wv] = t;
    __syncthreads();
    float tot = 0.f;
    #pragma unroll
    for (int i = 0; i < 8; ++i) tot += red[i];

    out[(size_t)b * N_DIM + n] = e / tot;
}

extern "C" void kernel_launch(void* const* d_in, const int* in_sizes, int n_in,
                              void* d_out, int out_size, void* d_ws, size_t ws_size,
                              hipStream_t stream) {
    const float* h_t  = (const float*)d_in[0];
    const float* s_t  = (const float*)d_in[1];
    const float* data = (const float*)d_in[2];
    const float* W_e  = (const float*)d_in[3];
    const float* U_e  = (const float*)d_in[4];
    const float* v_e  = (const float*)d_in[5];
    float* out = (float*)d_out;

    const size_t wq_elems     = (size_t)B_DIM * T_DIM;      // f32
    const size_t score_elems  = (size_t)B_DIM * N_DIM;      // f32
    const size_t u_elems      = (size_t)T_DIM * T_DIM;      // bf16

    float* wq      = (float*)d_ws;
    float* scores  = wq + wq_elems;
    __bf16* Uh     = (__bf16*)(scores + score_elems);

    wq_kernel<<<B_DIM, 256, 0, stream>>>(h_t, s_t, W_e, wq);
    uconv_kernel<<<(int)(u_elems / 512), 256, 0, stream>>>(U_e, Uh);
    fused13_kernel<<<256, 512, 0, stream>>>(data, Uh, v_e, wq, scores);
    softmax_kernel<<<B_DIM, 512, 0, stream>>>(scores, out);
}

// Round 16
// 157.008 us; speedup vs baseline: 1.9398x; 1.9398x over previous
//
#include <hip/hip_runtime.h>
#include <hip/hip_bf16.h>
#include <cmath>

#define T_DIM 512
#define N_DIM 512
#define M_DIM 256
#define B_DIM 256

typedef __bf16 bf16x8 __attribute__((ext_vector_type(8)));
typedef float  f32x4  __attribute__((ext_vector_type(4)));
typedef unsigned int u32;

#define WAITVM(N) asm volatile("s_waitcnt vmcnt(" #N ") lgkmcnt(0)" ::: "memory")
#define FENCED_BARRIER() do { __builtin_amdgcn_sched_barrier(0); \
                              __builtin_amdgcn_s_barrier();      \
                              __builtin_amdgcn_sched_barrier(0); } while (0)

__device__ __forceinline__ void gload16(const __bf16* g, __bf16* l) {
    __builtin_amdgcn_global_load_lds(
        (const __attribute__((address_space(1))) void*)g,
        (__attribute__((address_space(3))) void*)l, 16, 0, 0);
}

// bank-spread key (R9-R13 proven)
__device__ __forceinline__ int bkey(int r) { return ((r >> 3) ^ (r >> 1)) & 3; }

// pack hi16(H):hi16(L) in ONE v_perm_b32 (bf16 truncation; R13-validated)
__device__ __forceinline__ u32 pack_trunc(float hi, float lo) {
    return __builtin_amdgcn_perm(__builtin_bit_cast(u32, hi),
                                 __builtin_bit_cast(u32, lo), 0x07060302u);
}

// fast tanh (R10-validated)
__device__ __forceinline__ float ftanh(float x) {
    return 1.f - 2.f / (__expf(2.f * x) + 1.f);
}

// ---------------- precompute: U_e -> bf16 ----------------
__global__ __launch_bounds__(256) void uconv_kernel(
    const float* __restrict__ U, __bf16* __restrict__ Uh)
{
    const int i = (blockIdx.x * 256 + threadIdx.x) * 2;
    float2 v = *(const float2*)(U + i);
    Uh[i]   = (__bf16)v.x;
    Uh[i+1] = (__bf16)v.y;
}

// ---------------- wq[b,t] = concat(h,s) . W_e[t,:] ----------------
__global__ __launch_bounds__(256) void wq_kernel(
    const float* __restrict__ h_t, const float* __restrict__ s_t,
    const float* __restrict__ W_e, float* __restrict__ wq)
{
    __shared__ float q[2 * M_DIM];
    const int b = blockIdx.x;
    const int tid = threadIdx.x;
    q[tid]         = h_t[(size_t)b * M_DIM + tid];
    q[M_DIM + tid] = s_t[(size_t)b * M_DIM + tid];
    __syncthreads();
    for (int tt = tid; tt < T_DIM; tt += 256) {
        const float4* wrow = (const float4*)(W_e + (size_t)tt * (2 * M_DIM));
        float acc = 0.f;
        #pragma unroll 4
        for (int k4 = 0; k4 < (2 * M_DIM) / 4; ++k4) {
            float4 w = wrow[k4];
            acc += q[4*k4+0] * w.x + q[4*k4+1] * w.y
                 + q[4*k4+2] * w.z + q[4*k4+3] * w.w;
        }
        wq[(size_t)b * T_DIM + tt] = acc;
    }
}

// ---------------- fused: R13 dataflow + 3-ring B staged 2 ahead, counted vmcnt ----------------
// Per step k: frag reads; cvt pa(k+1)->As[(k+1)&1] (compiler wait drains ONLY pa:
// pa was issued BEFORE B(k+1) last step); issue pa(k+2); issue B(k+2)->ring (k+2)%3;
// MFMA; vmcnt(6) retires B(k+1) (age ~2 steps); raw fenced barrier (no auto drain).
__global__ __launch_bounds__(512, 2) void fused12_kernel(
    const float* __restrict__ data, const __bf16* __restrict__ Uh,
    const float* __restrict__ v_e, const float* __restrict__ wq,
    float* __restrict__ scores)
{
    __shared__ __align__(16) __bf16 As[2][128 * 32];   // 16 KB
    __shared__ __align__(16) __bf16 Bs[3][512 * 32];   // 96 KB (3-ring)
    __shared__ float sc2[4][128];

    const int wg   = blockIdx.x;
    const int bgrp = wg >> 2;
    const int nb   = wg & 3;

    const int tid  = threadIdx.x;
    const int lane = tid & 63;
    const int wid  = tid >> 6;
    const int wm   = wid >> 2;           // n-half
    const int wn   = wid & 3;            // s-quarter

    f32x4 acc[4][8];
    const f32x4 zero = {0.f, 0.f, 0.f, 0.f};
    #pragma unroll
    for (int i = 0; i < 4; ++i)
        #pragma unroll
        for (int j = 0; j < 8; ++j)
            acc[i][j] = zero;

    // A staging map (R11): rp = t-pair, nq -> 4 n rows, 32-lane coalesced
    const int rp = tid >> 5;
    const int nq = tid & 31;
    const int n0 = nq * 4;
    const float* Apan = data + ((size_t)bgrp * 4 * T_DIM) * N_DIM + nb * 128 + n0;

    // B staging (R9): source-side chunk swizzle, linear LDS dest
    const __bf16* Bb = Uh;
    const int r0   = tid >> 2;
    const int ce   = (((tid & 3) ^ bkey(r0)) * 8);

    const int fr = lane & 15;
    const int kb = (lane >> 4) * 8;

    int aoff[4];
    #pragma unroll
    for (int mi = 0; mi < 4; ++mi) {
        const int row = wm * 64 + mi * 16 + fr;
        aoff[mi] = row * 32 + (kb ^ (bkey(row) << 3));
    }
    int boff[8];
    #pragma unroll
    for (int ni = 0; ni < 8; ++ni) {
        const int row = wn * 128 + ni * 16 + fr;
        boff[ni] = row * 32 + (kb ^ (bkey(row) << 3));
    }

    float vev[8];
    #pragma unroll
    for (int ni = 0; ni < 8; ++ni)
        vev[ni] = v_e[wn * 128 + ni * 16 + fr];
    const int g = lane >> 4;

    float4 pa0, pa1;

#define CVT_STORE(DST)                                                        \
    {                                                                         \
        u32* As32_ = (u32*)(DST);                                             \
        const float lo_[4] = {pa0.x, pa0.y, pa0.z, pa0.w};                    \
        const float hi_[4] = {pa1.x, pa1.y, pa1.z, pa1.w};                    \
        _Pragma("unroll")                                                     \
        for (int j = 0; j < 4; ++j) {                                         \
            const u32 w_ = pack_trunc(hi_[j], lo_[j]);                        \
            const int key_ = bkey(n0 + j);                                    \
            As32_[(n0 + j) * 16 + (rp ^ (key_ << 2))] = w_;                   \
        }                                                                     \
    }

#define LOAD_PA(T)                                                            \
    {                                                                         \
        const float* sn_ = Apan + (size_t)(32 * (T) + 2 * rp) * N_DIM;        \
        pa0 = *(const float4*)sn_;                                            \
        pa1 = *(const float4*)(sn_ + N_DIM);                                  \
    }

#define STAGE_B(T, RING)                                                      \
    {                                                                         \
        const int kcol_ = ((T) & 15) << 5;                                    \
        _Pragma("unroll")                                                     \
        for (int i = 0; i < 4; ++i)                                           \
            gload16(Bb + (size_t)(i * 128 + r0) * T_DIM + kcol_ + ce,         \
                    &Bs[RING][0] + (size_t)i * 128 * 32 + tid * 8);           \
    }

// MODE: 0 steady (cvt + stage k+2 + vmcnt(6)), 1 = k==62 (cvt only + vmcnt(0)),
//       2 = k==63 (nothing; epilogue follows)
#define K_STEP(K, CURA, RINGC, RINGS, MODE)                                   \
    {                                                                         \
        bf16x8 a_[4], bv_[8];                                                 \
        _Pragma("unroll")                                                     \
        for (int mi = 0; mi < 4; ++mi)                                        \
            a_[mi] = *(const bf16x8*)&As[CURA][aoff[mi]];                     \
        _Pragma("unroll")                                                     \
        for (int ni = 0; ni < 8; ++ni)                                        \
            bv_[ni] = *(const bf16x8*)&Bs[RINGC][boff[ni]];                   \
        if ((MODE) <= 1) CVT_STORE(As[(CURA) ^ 1]);                           \
        if ((MODE) == 0) { LOAD_PA((K) + 2); STAGE_B((K) + 2, RINGS); }       \
        __builtin_amdgcn_s_setprio(1);                                        \
        _Pragma("unroll")                                                     \
        for (int mi = 0; mi < 4; ++mi)                                        \
            _Pragma("unroll")                                                 \
            for (int ni = 0; ni < 8; ++ni)                                    \
                acc[mi][ni] = __builtin_amdgcn_mfma_f32_16x16x32_bf16(        \
                    a_[mi], bv_[ni], acc[mi][ni], 0, 0, 0);                   \
        __builtin_amdgcn_s_setprio(0);                                        \
        if ((MODE) == 0)      { WAITVM(6); FENCED_BARRIER(); }                \
        else if ((MODE) == 1) { WAITVM(0); FENCED_BARRIER(); }                \
    }

#define PANEL_EPI(BIDX, DORESET)                                              \
    {                                                                         \
        const int b_ = bgrp * 4 + (BIDX);                                     \
        float wqv_[8];                                                        \
        _Pragma("unroll")                                                     \
        for (int ni = 0; ni < 8; ++ni)                                        \
            wqv_[ni] = wq[(size_t)b_ * T_DIM + wn * 128 + ni * 16 + fr];      \
        _Pragma("unroll")                                                     \
        for (int mi = 0; mi < 4; ++mi) {                                      \
            _Pragma("unroll")                                                 \
            for (int rg = 0; rg < 4; ++rg) {                                  \
                float part_ = 0.f;                                            \
                _Pragma("unroll")                                             \
                for (int ni = 0; ni < 8; ++ni)                                \
                    part_ += vev[ni] * ftanh(wqv_[ni] + acc[mi][ni][rg]);     \
                part_ += __shfl_xor(part_, 1);                                \
                part_ += __shfl_xor(part_, 2);                                \
                part_ += __shfl_xor(part_, 4);                                \
                part_ += __shfl_xor(part_, 8);                                \
                if (fr == 0)                                                  \
                    sc2[wn][wm * 64 + mi * 16 + 4 * g + rg] = part_;          \
            }                                                                 \
        }                                                                     \
        asm volatile("s_waitcnt lgkmcnt(0)" ::: "memory");                    \
        FENCED_BARRIER();                                                     \
        if (tid < 128) {                                                      \
            const float s_ = sc2[0][tid] + sc2[1][tid]                        \
                           + sc2[2][tid] + sc2[3][tid];                       \
            scores[(size_t)b_ * N_DIM + nb * 128 + tid] = s_;                 \
        }                                                                     \
        if (DORESET) {                                                        \
            _Pragma("unroll")                                                 \
            for (int i = 0; i < 4; ++i)                                       \
                _Pragma("unroll")                                             \
                for (int j = 0; j < 8; ++j)                                   \
                    acc[i][j] = zero;                                         \
        }                                                                     \
    }

    // ---- prologue: cvt t0->As[0]; B(0)->ring0; pa<-t1; B(1)->ring1
    LOAD_PA(0);
    CVT_STORE(As[0]);          // waits pa(t0) only
    STAGE_B(0, 0);
    LOAD_PA(1);
    STAGE_B(1, 1);
    WAITVM(6);                 // retire B(0) (keeps B(1) in flight; pa(t1) drains with it)
    FENCED_BARRIER();

    // ---- main loop: k = 0..59 (unroll 6 => static parity + ring indices)
    for (int m = 0; m < 10; ++m) {
        const int k6 = 6 * m;
        K_STEP(k6 + 0, 0, 0, 2, 0); if (((k6 + 0) & 15) == 15) PANEL_EPI((k6 + 0) >> 4, 1);
        K_STEP(k6 + 1, 1, 1, 0, 0); if (((k6 + 1) & 15) == 15) PANEL_EPI((k6 + 1) >> 4, 1);
        K_STEP(k6 + 2, 0, 2, 1, 0); if (((k6 + 2) & 15) == 15) PANEL_EPI((k6 + 2) >> 4, 1);
        K_STEP(k6 + 3, 1, 0, 2, 0); if (((k6 + 3) & 15) == 15) PANEL_EPI((k6 + 3) >> 4, 1);
        K_STEP(k6 + 4, 0, 1, 0, 0); if (((k6 + 4) & 15) == 15) PANEL_EPI((k6 + 4) >> 4, 1);
        K_STEP(k6 + 5, 1, 2, 1, 0); if (((k6 + 5) & 15) == 15) PANEL_EPI((k6 + 5) >> 4, 1);
    }

    // ---- peeled tail: k = 60..63
    K_STEP(60, 0, 0, 2, 0);
    K_STEP(61, 1, 1, 0, 0);    // stages B(63)->ring0, pa<-t63
    K_STEP(62, 0, 2, 0, 1);    // cvt t63->As[1]; vmcnt(0) retires B(63)
    K_STEP(63, 1, 0, 0, 2);    // compute only
    PANEL_EPI(3, 0);

#undef K_STEP
#undef PANEL_EPI
#undef CVT_STORE
#undef LOAD_PA
#undef STAGE_B
}

// ---------------- softmax over n ----------------
__global__ __launch_bounds__(512) void softmax_kernel(
    const float* __restrict__ scores, float* __restrict__ out)
{
    const int b = blockIdx.x;
    const int n = threadIdx.x;
    float s = scores[(size_t)b * N_DIM + n];

    float m = s;
    #pragma unroll
    for (int off = 1; off < 64; off <<= 1)
        m = fmaxf(m, __shfl_xor(m, off));
    __shared__ float red[8];
    const int wv = n >> 6;
    if ((n & 63) == 0) red[wv] = m;
    __syncthreads();
    float bm = red[0];
    #pragma unroll
    for (int i = 1; i < 8; ++i) bm = fmaxf(bm, red[i]);

    float e = expf(s - bm);
    float t = e;
    #pragma unroll
    for (int off = 1; off < 64; off <<= 1)
        t += __shfl_xor(t, off);
    __syncthreads();
    if ((n & 63) == 0) red[wv] = t;
    __syncthreads();
    float tot = 0.f;
    #pragma unroll
    for (int i = 0; i < 8; ++i) tot += red[i];

    out[(size_t)b * N_DIM + n] = e / tot;
}

extern "C" void kernel_launch(void* const* d_in, const int* in_sizes, int n_in,
                              void* d_out, int out_size, void* d_ws, size_t ws_size,
                              hipStream_t stream) {
    const float* h_t  = (const float*)d_in[0];
    const float* s_t  = (const float*)d_in[1];
    const float* data = (const float*)d_in[2];
    const float* W_e  = (const float*)d_in[3];
    const float* U_e  = (const float*)d_in[4];
    const float* v_e  = (const float*)d_in[5];
    float* out = (float*)d_out;

    const size_t wq_elems     = (size_t)B_DIM * T_DIM;      // f32
    const size_t score_elems  = (size_t)B_DIM * N_DIM;      // f32
    const size_t u_elems      = (size_t)T_DIM * T_DIM;      // bf16

    float* wq      = (float*)d_ws;
    float* scores  = wq + wq_elems;
    __bf16* Uh     = (__bf16*)(scores + score_elems);

    wq_kernel<<<B_DIM, 256, 0, stream>>>(h_t, s_t, W_e, wq);
    uconv_kernel<<<(int)(u_elems / 512), 256, 0, stream>>>(U_e, Uh);
    fused12_kernel<<<256, 512, 0, stream>>>(data, Uh, v_e, wq, scores);
    softmax_kernel<<<B_DIM, 512, 0, stream>>>(scores, out);
}